// Round 1
// baseline (111.526 us; speedup 1.0000x reference)
//
#include <hip/hip_runtime.h>

// VectorGauntTensorProduct — algebraic collapse to out = P @ K
//
// T[t,s,s']  = sum_g w[g] Yin[g,s] Yin[g,s'] Yout[g,t]          (25*81)
// V[lt,ls,ls',d] = sum_c Wx[ls,c] Wy[ls',c] Wz[lt,c,d]          (5*3*3*32)
// K[p=(s*9+s'), col=(d*25+t)] = T[t,s,s'] * V[l(t),l(s),l(s'),d] (81*800)
// P[n,v,p] = x[n,a,s] y[n,b,s'] - x[n,b,s] y[n,a,s']   (a,b)=cross pairs
// out[n,d,v,t] = sum_p P[n,v,p] * K[p, d*25+t]

#define NN     2048
#define NC     32
#define S_IN   9
#define S_OUT  25
#define GG     380
#define NCOLS  800   // NC * S_OUT
#define NP     81    // S_IN * S_IN

__device__ __forceinline__ int l_of_s(int s) {   // s in [0,9)
    return (s >= 4) ? 2 : ((s >= 1) ? 1 : 0);
}
__device__ __forceinline__ int l_of_t(int t) {   // t in [0,25)
    return (t >= 16) ? 4 : (t >= 9) ? 3 : (t >= 4) ? 2 : (t >= 1) ? 1 : 0;
}

// Kernel 1: T (2025 floats) and V (1440 floats)
__global__ void precompTV(const float* __restrict__ Wx, const float* __restrict__ Wy,
                          const float* __restrict__ Wz, const float* __restrict__ Yin,
                          const float* __restrict__ Yout, const float* __restrict__ wq,
                          float* __restrict__ T, float* __restrict__ V) {
    int idx = blockIdx.x * blockDim.x + threadIdx.x;
    if (idx < 25 * NP) {
        int t = idx / NP, r = idx % NP, s = r / 9, sp = r % 9;
        float acc = 0.f;
        for (int g = 0; g < GG; ++g)
            acc = fmaf(wq[g] * Yin[g * 9 + s], Yin[g * 9 + sp] * Yout[g * 25 + t], acc);
        T[idx] = acc;
    } else if (idx < 25 * NP + 5 * 3 * 3 * 32) {
        int i = idx - 25 * NP;
        int lt = i / 288, r = i % 288, ls = r / 96, lsp = (r % 96) / 32, d = r % 32;
        float acc = 0.f;
        for (int c = 0; c < 32; ++c)
            acc = fmaf(Wx[ls * 32 + c] * Wy[lsp * 32 + c], Wz[lt * 1024 + c * 32 + d], acc);
        V[i] = acc;
    }
}

// Kernel 2: K[81][800]
__global__ void precompK(const float* __restrict__ T, const float* __restrict__ V,
                         float* __restrict__ K) {
    int idx = blockIdx.x * blockDim.x + threadIdx.x;
    if (idx >= NP * NCOLS) return;
    int p = idx / NCOLS, col = idx % NCOLS;
    int s = p / 9, sp = p % 9, d = col / 25, t = col % 25;
    K[idx] = T[t * NP + p] * V[((l_of_t(t) * 3 + l_of_s(s)) * 3 + l_of_s(sp)) * 32 + d];
}

// Kernel 3: main. 4 samples per block; P[12][81] staged in LDS (broadcast reads).
// Each thread: cols {tid, tid+256, tid+512, tid+768(<800)}, acc[12 rows][4 cols].
__global__ __launch_bounds__(256) void gaunt_main(const float* __restrict__ x,
                                                  const float* __restrict__ y,
                                                  const float* __restrict__ K,
                                                  float* __restrict__ out) {
    __shared__ float xs[108];           // 4 n * 3 v * 9 s
    __shared__ float ys[108];
    __shared__ float Ps[12 * NP];       // 12 rows (4n x 3v) * 81

    const int tid = threadIdx.x;
    const int n0 = blockIdx.x * 4;

    if (tid < 108)       xs[tid]       = x[n0 * 27 + tid];
    else if (tid < 216)  ys[tid - 108] = y[n0 * 27 + (tid - 108)];
    __syncthreads();

    for (int idx = tid; idx < 12 * NP; idx += 256) {
        int row = idx / NP, p = idx % NP;
        int ni = row / 3, v = row % 3, s = p / 9, sp = p % 9;
        int a = (v == 0) ? 1 : ((v == 1) ? 2 : 0);
        int b = (v == 0) ? 2 : ((v == 1) ? 0 : 1);
        Ps[idx] = xs[ni * 27 + a * 9 + s] * ys[ni * 27 + b * 9 + sp]
                - xs[ni * 27 + b * 9 + s] * ys[ni * 27 + a * 9 + sp];
    }
    __syncthreads();

    float acc[12][4];
#pragma unroll
    for (int r = 0; r < 12; ++r)
#pragma unroll
        for (int j = 0; j < 4; ++j) acc[r][j] = 0.f;

    for (int p = 0; p < NP; ++p) {
        float pv[12];
#pragma unroll
        for (int r = 0; r < 12; ++r) pv[r] = Ps[r * NP + p];  // LDS broadcast
#pragma unroll
        for (int j = 0; j < 4; ++j) {
            int col = tid + 256 * j;
            if (col < NCOLS) {
                float kv = K[p * NCOLS + col];
#pragma unroll
                for (int r = 0; r < 12; ++r) acc[r][j] = fmaf(pv[r], kv, acc[r][j]);
            }
        }
    }

#pragma unroll
    for (int j = 0; j < 4; ++j) {
        int col = tid + 256 * j;
        if (col < NCOLS) {
            int d = col / 25, t = col % 25;
#pragma unroll
            for (int r = 0; r < 12; ++r) {
                int ni = r / 3, v = r % 3;
                out[(size_t)(n0 + ni) * 2400 + d * 75 + v * 25 + t] = acc[r][j];
            }
        }
    }
}

extern "C" void kernel_launch(void* const* d_in, const int* in_sizes, int n_in,
                              void* d_out, int out_size, void* d_ws, size_t ws_size,
                              hipStream_t stream) {
    const float* x    = (const float*)d_in[0];
    const float* y    = (const float*)d_in[1];
    const float* Wx   = (const float*)d_in[2];
    const float* Wy   = (const float*)d_in[3];
    const float* Wz   = (const float*)d_in[4];
    const float* Yin  = (const float*)d_in[5];
    const float* Yout = (const float*)d_in[6];
    const float* wq   = (const float*)d_in[7];
    float* out = (float*)d_out;

    float* T = (float*)d_ws;        // 2025
    float* V = T + 25 * NP;         // 1440
    float* K = V + 5 * 3 * 3 * 32;  // 64800

    precompTV<<<14, 256, 0, stream>>>(Wx, Wy, Wz, Yin, Yout, wq, T, V);
    precompK<<<(NP * NCOLS + 255) / 256, 256, 0, stream>>>(T, V, K);
    gaunt_main<<<NN / 4, 256, 0, stream>>>(x, y, K, out);
}

// Round 2
// 64.999 us; speedup vs baseline: 1.7158x; 1.7158x over previous
//
#include <hip/hip_runtime.h>

// VectorGauntTensorProduct — algebraic collapse to out = P @ K
//
// T[t,s,s']  = sum_g w[g] Yin[g,s] Yin[g,s'] Yout[g,t]          (25*81)
// V[lt,ls,ls',d] = sum_c Wx[ls,c] Wy[ls',c] Wz[lt,c,d]          (5*3*3*32)
// K[p=(s*9+s'), col=(d*25+t)] = T[t,s,s'] * V[l(t),l(s),l(s'),d] (81*800)
// P[n,v,p] = x[n,a,s] y[n,b,s'] - x[n,b,s] y[n,a,s']   (a,b)=cross pairs
// out[n,d,v,t] = sum_p P[n,v,p] * K[p, d*25+t]

#define NN     2048
#define NC     32
#define S_IN   9
#define S_OUT  25
#define GG     380
#define NCOLS  800   // NC * S_OUT
#define NP     81    // S_IN * S_IN

__device__ __forceinline__ int l_of_s(int s) {   // s in [0,9)
    return (s >= 4) ? 2 : ((s >= 1) ? 1 : 0);
}
__device__ __forceinline__ int l_of_t(int t) {   // t in [0,25)
    return (t >= 16) ? 4 : (t >= 9) ? 3 : (t >= 4) ? 2 : (t >= 1) ? 1 : 0;
}

// Kernel 1: T (2025 floats) and V (1440 floats)
__global__ void precompTV(const float* __restrict__ Wx, const float* __restrict__ Wy,
                          const float* __restrict__ Wz, const float* __restrict__ Yin,
                          const float* __restrict__ Yout, const float* __restrict__ wq,
                          float* __restrict__ T, float* __restrict__ V) {
    int idx = blockIdx.x * blockDim.x + threadIdx.x;
    if (idx < 25 * NP) {
        int t = idx / NP, r = idx % NP, s = r / 9, sp = r % 9;
        float acc = 0.f;
        for (int g = 0; g < GG; ++g)
            acc = fmaf(wq[g] * Yin[g * 9 + s], Yin[g * 9 + sp] * Yout[g * 25 + t], acc);
        T[idx] = acc;
    } else if (idx < 25 * NP + 5 * 3 * 3 * 32) {
        int i = idx - 25 * NP;
        int lt = i / 288, r = i % 288, ls = r / 96, lsp = (r % 96) / 32, d = r % 32;
        float acc = 0.f;
        for (int c = 0; c < 32; ++c)
            acc = fmaf(Wx[ls * 32 + c] * Wy[lsp * 32 + c], Wz[lt * 1024 + c * 32 + d], acc);
        V[i] = acc;
    }
}

// Kernel 2: K[81][800]
__global__ void precompK(const float* __restrict__ T, const float* __restrict__ V,
                         float* __restrict__ K) {
    int idx = blockIdx.x * blockDim.x + threadIdx.x;
    if (idx >= NP * NCOLS) return;
    int p = idx / NCOLS, col = idx % NCOLS;
    int s = p / 9, sp = p % 9, d = col / 25, t = col % 25;
    K[idx] = T[t * NP + p] * V[((l_of_t(t) * 3 + l_of_s(s)) * 3 + l_of_s(sp)) * 32 + d];
}

// Kernel 3: main GEMM-like contraction.
// 4 samples/block (12 rows), 256 threads. Cols: j=0..2 full (768), j=3 only tid<32.
// Ps stored transposed [p][16] so each p-iter is 3x ds_read_b128 broadcast.
__global__ __launch_bounds__(256) void gaunt_main(const float* __restrict__ x,
                                                  const float* __restrict__ y,
                                                  const float* __restrict__ K,
                                                  float* __restrict__ out) {
    __shared__ float xs[108];            // 4 n * 3 v * 9 s
    __shared__ float ys[108];
    __shared__ __align__(16) float Ps[NP][16];  // [p][row], rows 0..11 used

    const int tid = threadIdx.x;
    const int n0 = blockIdx.x * 4;

    if (tid < 108)       xs[tid]       = x[n0 * 27 + tid];
    else if (tid < 216)  ys[tid - 108] = y[n0 * 27 + (tid - 108)];
    __syncthreads();

    for (int idx = tid; idx < 12 * NP; idx += 256) {
        int p = idx / 12, row = idx % 12;
        int ni = row / 3, v = row % 3;
        int s = p / 9, sp = p % 9;
        int a = (v == 0) ? 1 : ((v == 1) ? 2 : 0);
        int b = (v == 0) ? 2 : ((v == 1) ? 0 : 1);
        Ps[p][row] = xs[ni * 27 + a * 9 + s] * ys[ni * 27 + b * 9 + sp]
                   - xs[ni * 27 + b * 9 + s] * ys[ni * 27 + a * 9 + sp];
    }
    __syncthreads();

    float acc[12][4];
#pragma unroll
    for (int r = 0; r < 12; ++r)
#pragma unroll
        for (int j = 0; j < 4; ++j) acc[r][j] = 0.f;

    const float* Kt = K + tid;
    for (int p = 0; p < NP; ++p) {
        const float4 q0 = *(const float4*)(&Ps[p][0]);
        const float4 q1 = *(const float4*)(&Ps[p][4]);
        const float4 q2 = *(const float4*)(&Ps[p][8]);
        float pv[12];
        pv[0] = q0.x; pv[1] = q0.y; pv[2]  = q0.z; pv[3]  = q0.w;
        pv[4] = q1.x; pv[5] = q1.y; pv[6]  = q1.z; pv[7]  = q1.w;
        pv[8] = q2.x; pv[9] = q2.y; pv[10] = q2.z; pv[11] = q2.w;

        const float* Kp = Kt + p * NCOLS;
        float kk[3];
        kk[0] = Kp[0]; kk[1] = Kp[256]; kk[2] = Kp[512];
#pragma unroll
        for (int j = 0; j < 3; ++j)
#pragma unroll
            for (int r = 0; r < 12; ++r)
                acc[r][j] = fmaf(pv[r], kk[j], acc[r][j]);

        if (tid < 32) {                   // wave-uniform skip for waves 1..3
            float k3 = Kp[768];
#pragma unroll
            for (int r = 0; r < 12; ++r)
                acc[r][3] = fmaf(pv[r], k3, acc[r][3]);
        }
    }

#pragma unroll
    for (int j = 0; j < 4; ++j) {
        if (j < 3 || tid < 32) {
            int col = tid + 256 * j;
            int d = col / 25, t = col % 25;
#pragma unroll
            for (int r = 0; r < 12; ++r) {
                int ni = r / 3, v = r % 3;
                out[(size_t)(n0 + ni) * 2400 + d * 75 + v * 25 + t] = acc[r][j];
            }
        }
    }
}

extern "C" void kernel_launch(void* const* d_in, const int* in_sizes, int n_in,
                              void* d_out, int out_size, void* d_ws, size_t ws_size,
                              hipStream_t stream) {
    const float* x    = (const float*)d_in[0];
    const float* y    = (const float*)d_in[1];
    const float* Wx   = (const float*)d_in[2];
    const float* Wy   = (const float*)d_in[3];
    const float* Wz   = (const float*)d_in[4];
    const float* Yin  = (const float*)d_in[5];
    const float* Yout = (const float*)d_in[6];
    const float* wq   = (const float*)d_in[7];
    float* out = (float*)d_out;

    float* T = (float*)d_ws;        // 2025
    float* V = T + 25 * NP;         // 1440
    float* K = V + 5 * 3 * 3 * 32;  // 64800

    precompTV<<<14, 256, 0, stream>>>(Wx, Wy, Wz, Yin, Yout, wq, T, V);
    precompK<<<(NP * NCOLS + 255) / 256, 256, 0, stream>>>(T, V, K);
    gaunt_main<<<NN / 4, 256, 0, stream>>>(x, y, K, out);
}

// Round 3
// 50.193 us; speedup vs baseline: 2.2220x; 1.2950x over previous
//
#include <hip/hip_runtime.h>

// VectorGauntTensorProduct — algebraic collapse to out = P @ K
//
// A[p,g]   = wq[g] * Yin[g,s] * Yin[g,s']           (p = s*9+s', 81*380)
// T[t,p]   = sum_g A[p,g] * Yout[g,t]               (25*81)
// V[lt,ls,ls',d] = sum_c Wx[ls,c] Wy[lsp,c] Wz[lt,c,d]
// Kpad[p, d*32+t] = T[t,p] * V[l(t),l(s),l(s'),d]   (84*1024, zero-padded)
// P[n,v,p] = x[n,a,s] y[n,b,s'] - x[n,b,s] y[n,a,s']
// out[n,d,v,t] = sum_p P[n,v,p] * Kpad[p, d*32+t]

#define NP     81
#define NPP    84          // p padded to 21 chunks of 4
#define NCP    1024        // cols padded: 32 d * 32 t (t<25 valid)
#define GG     380
#define CHUNK  4
#define NCHUNK 21

__device__ __forceinline__ int l_of_s(int s) { return (s >= 4) ? 2 : ((s >= 1) ? 1 : 0); }
__device__ __forceinline__ int l_of_t(int t) {
    return (t >= 16) ? 4 : (t >= 9) ? 3 : (t >= 4) ? 2 : (t >= 1) ? 1 : 0;
}

// P1: A[81][380], YoutT[25][380], V[5][3][3][32] — all embarrassingly parallel
__global__ void precompAux(const float* __restrict__ Wx, const float* __restrict__ Wy,
                           const float* __restrict__ Wz, const float* __restrict__ Yin,
                           const float* __restrict__ Yout, const float* __restrict__ wq,
                           float* __restrict__ A, float* __restrict__ YT,
                           float* __restrict__ V) {
    int idx = blockIdx.x * blockDim.x + threadIdx.x;
    if (idx < NP * GG) {
        int p = idx / GG, g = idx % GG, s = p / 9, sp = p % 9;
        A[idx] = wq[g] * Yin[g * 9 + s] * Yin[g * 9 + sp];
    } else if (idx < NP * GG + 25 * GG) {
        int i = idx - NP * GG, t = i / GG, g = i % GG;
        YT[i] = Yout[g * 25 + t];
    } else if (idx < NP * GG + 25 * GG + 1440) {
        int i = idx - NP * GG - 25 * GG;
        int lt = i / 288, r = i % 288, ls = r / 96, lsp = (r % 96) / 32, d = r % 32;
        float acc = 0.f;
        for (int c = 0; c < 32; ++c)
            acc = fmaf(Wx[ls * 32 + c] * Wy[lsp * 32 + c], Wz[lt * 1024 + c * 32 + d], acc);
        V[i] = acc;
    }
}

// P2: T[t][p] = float4-dot(A[p][:], YT[t][:]) — 95 independent f4 pairs
__global__ void precompT(const float* __restrict__ A, const float* __restrict__ YT,
                         float* __restrict__ T) {
    int idx = blockIdx.x * blockDim.x + threadIdx.x;
    if (idx >= 25 * NP) return;
    int t = idx / NP, p = idx % NP;
    const float4* a4 = (const float4*)(A + p * GG);   // 380*4B row, 16B aligned
    const float4* y4 = (const float4*)(YT + t * GG);
    float acc = 0.f;
#pragma unroll 5
    for (int k = 0; k < GG / 4; ++k) {
        float4 a = a4[k], yv = y4[k];
        acc = fmaf(a.x, yv.x, acc);
        acc = fmaf(a.y, yv.y, acc);
        acc = fmaf(a.z, yv.z, acc);
        acc = fmaf(a.w, yv.w, acc);
    }
    T[idx] = acc;
}

// P3: padded K[84][1024], zeros for p>=81 or t>=25
__global__ void precompKpad(const float* __restrict__ T, const float* __restrict__ V,
                            float* __restrict__ Kpad) {
    int idx = blockIdx.x * blockDim.x + threadIdx.x;
    if (idx >= NPP * NCP) return;
    int p = idx / NCP, col = idx % NCP;
    int d = col >> 5, t = col & 31;
    float val = 0.f;
    if (p < NP && t < 25) {
        int s = p / 9, sp = p % 9;
        val = T[t * NP + p] * V[((l_of_t(t) * 3 + l_of_s(s)) * 3 + l_of_s(sp)) * 32 + d];
    }
    Kpad[idx] = val;
}

// Main: C[6144 rows][1024 padded cols] = P @ Kpad.
// Block: 4 samples (12 rows), 256 threads, thread owns 4 consecutive padded cols
// (d = tid/8, t0 = (tid%8)*4). K streamed through LDS in 21 chunks of 4 p-rows,
// register double-buffered (issue loads early, ds_write late, 1 barrier/chunk).
__global__ __launch_bounds__(256, 4) void gaunt_main(const float* __restrict__ x,
                                                     const float* __restrict__ y,
                                                     const float* __restrict__ Kpad,
                                                     float* __restrict__ out) {
    __shared__ float xs[108];                      // 4n * 3v * 9s
    __shared__ float ys[108];
    __shared__ __align__(16) float Ps[NPP][16];    // [p][row], rows 0..11 used
    __shared__ __align__(16) float Kb[2][CHUNK * NCP];  // 2 * 16KB

    const int tid = threadIdx.x;
    const int n0 = blockIdx.x * 4;

    if (tid < 108)       xs[tid]       = x[n0 * 27 + tid];
    else if (tid < 216)  ys[tid - 108] = y[n0 * 27 + (tid - 108)];
    __syncthreads();

    for (int idx = tid; idx < NPP * 12; idx += 256) {   // 1008 -> 4 iters
        int p = idx / 12, row = idx % 12;
        float v = 0.f;
        if (p < NP) {
            int ni = row / 3, vv = row % 3;
            int s = p / 9, sp = p % 9;
            int a = (vv == 0) ? 1 : ((vv == 1) ? 2 : 0);
            int b = (vv == 0) ? 2 : ((vv == 1) ? 0 : 1);
            v = xs[ni * 27 + a * 9 + s] * ys[ni * 27 + b * 9 + sp]
              - xs[ni * 27 + b * 9 + s] * ys[ni * 27 + a * 9 + sp];
        }
        Ps[p][row] = v;
    }

    // stage chunk 0
    const float4* K4 = (const float4*)Kpad;
    float4 st[4];
#pragma unroll
    for (int k = 0; k < 4; ++k) st[k] = K4[tid + 256 * k];
#pragma unroll
    for (int k = 0; k < 4; ++k)
        *((float4*)&Kb[0][(tid + 256 * k) * 4]) = st[k];
    __syncthreads();

    float acc[12][4];
#pragma unroll
    for (int r = 0; r < 12; ++r)
#pragma unroll
        for (int j = 0; j < 4; ++j) acc[r][j] = 0.f;

    int cur = 0;
    for (int c = 0; c < NCHUNK; ++c) {
        if (c < NCHUNK - 1) {   // issue next chunk's loads early (hide L2 latency)
#pragma unroll
            for (int k = 0; k < 4; ++k)
                st[k] = K4[(c + 1) * (CHUNK * NCP / 4) + tid + 256 * k];
        }
#pragma unroll
        for (int pp = 0; pp < CHUNK; ++pp) {
            const int p = c * CHUNK + pp;
            const float4 q0 = *(const float4*)&Ps[p][0];   // LDS broadcast
            const float4 q1 = *(const float4*)&Ps[p][4];
            const float4 q2 = *(const float4*)&Ps[p][8];
            const float4 kk = *(const float4*)&Kb[cur][pp * NCP + tid * 4];
            float pv[12] = {q0.x, q0.y, q0.z, q0.w, q1.x, q1.y,
                            q1.z, q1.w, q2.x, q2.y, q2.z, q2.w};
            float kv[4] = {kk.x, kk.y, kk.z, kk.w};
#pragma unroll
            for (int r = 0; r < 12; ++r)
#pragma unroll
                for (int j = 0; j < 4; ++j)
                    acc[r][j] = fmaf(pv[r], kv[j], acc[r][j]);
        }
        if (c < NCHUNK - 1) {   // compiler inserts vmcnt before these writes
#pragma unroll
            for (int k = 0; k < 4; ++k)
                *((float4*)&Kb[cur ^ 1][(tid + 256 * k) * 4]) = st[k];
        }
        __syncthreads();
        cur ^= 1;
    }

    // epilogue: scalar stores (out rows not 16B aligned: stride 25 floats)
    const int d = tid >> 3, t0 = (tid & 7) * 4;
#pragma unroll
    for (int j = 0; j < 4; ++j) {
        int t = t0 + j;
        if (t < 25) {
#pragma unroll
            for (int r = 0; r < 12; ++r) {
                int ni = r / 3, v = r % 3;
                out[(size_t)(n0 + ni) * 2400 + d * 75 + v * 25 + t] = acc[r][j];
            }
        }
    }
}

extern "C" void kernel_launch(void* const* d_in, const int* in_sizes, int n_in,
                              void* d_out, int out_size, void* d_ws, size_t ws_size,
                              hipStream_t stream) {
    const float* x    = (const float*)d_in[0];
    const float* y    = (const float*)d_in[1];
    const float* Wx   = (const float*)d_in[2];
    const float* Wy   = (const float*)d_in[3];
    const float* Wz   = (const float*)d_in[4];
    const float* Yin  = (const float*)d_in[5];
    const float* Yout = (const float*)d_in[6];
    const float* wq   = (const float*)d_in[7];
    float* out = (float*)d_out;

    float* A  = (float*)d_ws;            // 81*380  = 30780
    float* YT = A + NP * GG;             // 25*380  = 9500
    float* V  = YT + 25 * GG;            // 1440
    float* T  = V + 1440;                // 2025
    float* K  = T + 25 * NP;             // 84*1024 = 86016

    int auxTotal = NP * GG + 25 * GG + 1440;
    precompAux<<<(auxTotal + 255) / 256, 256, 0, stream>>>(Wx, Wy, Wz, Yin, Yout, wq, A, YT, V);
    precompT<<<(25 * NP + 255) / 256, 256, 0, stream>>>(A, YT, T);
    precompKpad<<<(NPP * NCP + 255) / 256, 256, 0, stream>>>(T, V, K);
    gaunt_main<<<2048 / 4, 256, 0, stream>>>(x, y, K, out);
}

// Round 7
// 33.863 us; speedup vs baseline: 3.2935x; 1.4822x over previous
//
#include <hip/hip_runtime.h>

// VectorGauntTensorProduct — factored algebraic collapse (r6 + Vs-staging fix).
//
// A[p,g]   = wq[g] Yin[g,s] Yin[g,s']                       (p = s*9+s', 81x380)
// T[t,pp]  = sum_g A[perm(pp),g] Yout[g,t]                  (25x84, block-permuted, pads 0)
// V[lt,b,d]= sum_c Wx[ls,c] Wy[lsp,c] Wz[lt,c,d]            (b = ls*3+lsp, 5x9x32)
// P[row,pp]= x[n,a,s] y[n,b,s'] - x[n,b,s] y[n,a,s']        (row = ni*3+v, permuted cols)
// Z[row,t,b] = sum_{pp in block b} P[row,pp] T[t,pp]        (9 contiguous ranges)
// out[n,d,v,t] = sum_b Z[row,t,b] V[l(t),b,d]
//
// Block permutation: p=(s,sp) ordered by b=(l(s)*3+l(sp)), contiguous.
// Block sizes {1,3,5,3,9,15,5,15,25}, starts {0,1,4,9,12,21,36,41,56,81}.
//
// BUG HISTORY (r4-r6 failures): `if (tid < 360) Vs4[tid] = Vg4[tid]` with
// blockDim=256 leaves Vs floats [1024,1440) (lt>=3,b>=5) unstaged -> stage B
// read stale LDS for t>=9. Fixed below with a strided loop. r4 additionally
// had a Zout/Vs overlay race (fixed in r5).

#define GG 380

// decode permuted index pp (<81) -> (s, sp)
__device__ __forceinline__ void decode(int pp, int& s, int& sp) {
    int b, off;
    if (pp < 12) {
        if (pp < 1)       { b = 0; off = pp; }
        else if (pp < 4)  { b = 1; off = pp - 1; }
        else if (pp < 9)  { b = 2; off = pp - 4; }
        else              { b = 3; off = pp - 9; }
    } else if (pp < 36) {
        if (pp < 21)      { b = 4; off = pp - 12; }
        else              { b = 5; off = pp - 21; }
    } else {
        if (pp < 41)      { b = 6; off = pp - 36; }
        else if (pp < 56) { b = 7; off = pp - 41; }
        else              { b = 8; off = pp - 56; }
    }
    int ls = b / 3, lsp = b % 3, w = 2 * lsp + 1;
    s  = ls * ls + off / w;
    sp = lsp * lsp + off % w;
}

__device__ __forceinline__ float dotr(const float* a, const float* b, int lo, int hi) {
    float z = 0.f;
#pragma unroll
    for (int q = lo; q < hi; ++q) z = fmaf(a[q], b[q], z);
    return z;
}

// ---- P1: A[81][380], YT[25][380], V[5][9][32] — embarrassingly parallel
__global__ void precompAux(const float* __restrict__ Wx, const float* __restrict__ Wy,
                           const float* __restrict__ Wz, const float* __restrict__ Yin,
                           const float* __restrict__ Yout, const float* __restrict__ wq,
                           float* __restrict__ A, float* __restrict__ YT,
                           float* __restrict__ V) {
    int idx = blockIdx.x * blockDim.x + threadIdx.x;
    if (idx < 81 * GG) {
        int p = idx / GG, g = idx % GG, s = p / 9, sp = p % 9;
        A[idx] = wq[g] * Yin[g * 9 + s] * Yin[g * 9 + sp];
    } else if (idx < 81 * GG + 25 * GG) {
        int i = idx - 81 * GG, t = i / GG, g = i % GG;
        YT[i] = Yout[g * 25 + t];
    } else if (idx < 81 * GG + 25 * GG + 1440) {
        int i = idx - 81 * GG - 25 * GG;
        int lt = i / 288, r = i % 288, b = r / 32, d = r % 32;
        int ls = b / 3, lsp = b % 3;
        float acc = 0.f;
        for (int c = 0; c < 32; ++c)
            acc = fmaf(Wx[ls * 32 + c] * Wy[lsp * 32 + c],
                       Wz[lt * 1024 + c * 32 + d], acc);
        V[i] = acc;
    }
}

// ---- P2: T[t][84] permuted+padded, via float4 dots
__global__ void precompT84(const float* __restrict__ A, const float* __restrict__ YT,
                           float* __restrict__ Tg) {
    int idx = blockIdx.x * blockDim.x + threadIdx.x;
    if (idx >= 25 * 84) return;
    int t = idx / 84, pp = idx % 84;
    float acc = 0.f;
    if (pp < 81) {
        int s, sp; decode(pp, s, sp);
        int p = s * 9 + sp;
        const float4* a4 = (const float4*)(A + p * GG);
        const float4* y4 = (const float4*)(YT + t * GG);
#pragma unroll 5
        for (int k = 0; k < GG / 4; ++k) {
            float4 a = a4[k], yv = y4[k];
            acc = fmaf(a.x, yv.x, acc); acc = fmaf(a.y, yv.y, acc);
            acc = fmaf(a.z, yv.z, acc); acc = fmaf(a.w, yv.w, acc);
        }
    }
    Tg[idx] = acc;
}

// ---- main: 2 samples/block, 1024 blocks, 256 threads. NO LDS OVERLAYS.
// LDS floats: xs[0,54) ys[54,108) Ps[108,612) Ts[612,2712) Vs[2712,4152)
//             Z[4152,5952) Zout[5952,10752)  — total 10752 (43 KB), all disjoint.
__global__ __launch_bounds__(256) void gaunt_main(const float* __restrict__ x,
                                                  const float* __restrict__ y,
                                                  const float* __restrict__ Tg,
                                                  const float* __restrict__ Vg,
                                                  float* __restrict__ out) {
    __shared__ __align__(16) float smem[10752];
    float* xs   = smem;            // 54
    float* ys   = smem + 54;       // 54
    float* Ps   = smem + 108;      // 6*84
    float* Ts   = smem + 612;      // 25*84
    float* Vs   = smem + 2712;     // 1440
    float* Z    = smem + 4152;     // 6*300
    float* Zout = smem + 5952;     // 4800

    const int tid = threadIdx.x;
    const int n0 = blockIdx.x * 2;

    if (tid < 54)       xs[tid]      = x[n0 * 27 + tid];
    else if (tid < 108) ys[tid - 54] = y[n0 * 27 + tid - 54];
    for (int i = tid; i < 525; i += 256)            // Ts: 2100 floats
        ((float4*)Ts)[i] = ((const float4*)Tg)[i];
    for (int i = tid; i < 360; i += 256)            // Vs: 1440 floats (FIXED:
        ((float4*)Vs)[i] = ((const float4*)Vg)[i];  //  was `if (tid<360)` w/ 256 thr)
    __syncthreads();

    // P[row][84] in permuted column order (pads zero, never read by stage A)
    for (int idx = tid; idx < 504; idx += 256) {
        int row = idx / 84, pp = idx % 84;
        float v = 0.f;
        if (pp < 81) {
            int s, sp; decode(pp, s, sp);
            int ni = row / 3, vv = row % 3;
            int a = (vv == 0) ? 1 : ((vv == 1) ? 2 : 0);
            int b = (vv == 0) ? 2 : ((vv == 1) ? 0 : 1);
            v = xs[ni * 27 + a * 9 + s] * ys[ni * 27 + b * 9 + sp]
              - xs[ni * 27 + b * 9 + s] * ys[ni * 27 + a * 9 + sp];
        }
        Ps[idx] = v;
    }
    __syncthreads();

    // Stage A: 150 (t,row) pairs; 9 contiguous-range dots -> Z[row][t*12 + b]
    for (int pair = tid; pair < 150; pair += 256) {
        int t = pair / 6, row = pair % 6;
        const float* Pr = Ps + row * 84;
        const float* Tr = Ts + t * 84;
        float* zp = Z + row * 300 + t * 12;
        zp[0] = dotr(Pr, Tr, 0, 1);
        zp[1] = dotr(Pr, Tr, 1, 4);
        zp[2] = dotr(Pr, Tr, 4, 9);
        zp[3] = dotr(Pr, Tr, 9, 12);
        zp[4] = dotr(Pr, Tr, 12, 21);
        zp[5] = dotr(Pr, Tr, 21, 36);
        zp[6] = dotr(Pr, Tr, 36, 41);
        zp[7] = dotr(Pr, Tr, 41, 56);
        zp[8] = dotr(Pr, Tr, 56, 81);
    }
    __syncthreads();

    // Stage B: thread = (d = tid&31, g = tid>>5); g<6 -> row g
    {
        const int d = tid & 31, g = tid >> 5;
        if (g < 6) {
            const int row = g;
            const int zo = (row / 3) * 2400 + d * 75 + (row % 3) * 25;
#pragma unroll
            for (int t = 0; t < 25; ++t) {
                const int lt = (t >= 16) ? 4 : (t >= 9) ? 3 : (t >= 4) ? 2
                             : (t >= 1) ? 1 : 0;
                const float* vb = Vs + lt * 288 + d;
                const float* zp = Z + row * 300 + t * 12;
                float acc = zp[8] * vb[256];
                acc = fmaf(zp[0], vb[0],   acc);
                acc = fmaf(zp[1], vb[32],  acc);
                acc = fmaf(zp[2], vb[64],  acc);
                acc = fmaf(zp[3], vb[96],  acc);
                acc = fmaf(zp[4], vb[128], acc);
                acc = fmaf(zp[5], vb[160], acc);
                acc = fmaf(zp[6], vb[192], acc);
                acc = fmaf(zp[7], vb[224], acc);
                Zout[zo + t] = acc;
            }
        }
    }
    __syncthreads();

    // coalesced copy-out: 4800 floats = 1200 float4, contiguous
    float4* og = (float4*)(out + (size_t)n0 * 2400);
    const float4* zo4 = (const float4*)Zout;
    for (int i = tid; i < 1200; i += 256) og[i] = zo4[i];
}

extern "C" void kernel_launch(void* const* d_in, const int* in_sizes, int n_in,
                              void* d_out, int out_size, void* d_ws, size_t ws_size,
                              hipStream_t stream) {
    const float* x    = (const float*)d_in[0];
    const float* y    = (const float*)d_in[1];
    const float* Wx   = (const float*)d_in[2];
    const float* Wy   = (const float*)d_in[3];
    const float* Wz   = (const float*)d_in[4];
    const float* Yin  = (const float*)d_in[5];
    const float* Yout = (const float*)d_in[6];
    const float* wq   = (const float*)d_in[7];
    float* out = (float*)d_out;

    float* A  = (float*)d_ws;        // 81*380 = 30780
    float* YT = A + 81 * GG;         // 25*380 = 9500
    float* Vg = YT + 25 * GG;        // 1440   (byte off 161120, 16B-aligned)
    float* Tg = Vg + 1440;           // 25*84 = 2100 (byte off 166880, 16B-aligned)

    int auxTotal = 81 * GG + 25 * GG + 1440;   // 41720
    precompAux<<<(auxTotal + 255) / 256, 256, 0, stream>>>(Wx, Wy, Wz, Yin, Yout, wq,
                                                           A, YT, Vg);
    precompT84<<<(25 * 84 + 255) / 256, 256, 0, stream>>>(A, YT, Tg);
    gaunt_main<<<1024, 256, 0, stream>>>(x, y, Tg, Vg, out);
}

// Round 8
// 33.650 us; speedup vs baseline: 3.3143x; 1.0063x over previous
//
#include <hip/hip_runtime.h>

// VectorGauntTensorProduct — factored algebraic collapse, vectorized stages.
//
// A[p,g]   = wq[g] Yin[g,s] Yin[g,s']                       (p = s*9+s', 81x380)
// T[t,pq]  = sum_g A[perm(pq),g] Yout[g,t]                  (25x100, block-padded)
// V[lt,b,d]= sum_c Wx[ls,c] Wy[lsp,c] Wz[lt,c,d]            (b = ls*3+lsp, 5x9x32)
// P[row,pq]= x[n,a,s] y[n,b,s'] - x[n,b,s] y[n,a,s']        (row = ni*3+v)
// Z[row,t,b] = sum_{pq in block b} P[row,pq] T[t,pq]        (f4 chunk ranges)
// out[n,d,v,t] = sum_b Z[row,t,b] V[l(t),b,d]
//
// Padded block layout: block b = ls*3+lsp, real sizes {1,3,5,3,9,15,5,15,25}
// padded to /4: {4,4,8,4,12,16,8,16,28}, starts {0,4,8,16,20,32,48,56,72}, tot 100.
// Pads are 0.0 in BOTH T and P -> contribute nothing.
//
// BUG HISTORY: r4 Zout/Vs overlay race; r4-r6 `if(tid<360)` staging with 256
// threads left Vs[1024:1440) unstaged. All staging loops are STRIDED now.

#define GG 380

// decode padded index pq (<100) -> (s, sp); false if pad slot
__device__ __forceinline__ bool decode2(int pq, int& s, int& sp) {
    int b, off;
    if (pq < 16) {
        if (pq < 4)       { b = 0; off = pq; }
        else if (pq < 8)  { b = 1; off = pq - 4; }
        else              { b = 2; off = pq - 8; }
    } else if (pq < 48) {
        if (pq < 20)      { b = 3; off = pq - 16; }
        else if (pq < 32) { b = 4; off = pq - 20; }
        else              { b = 5; off = pq - 32; }
    } else {
        if (pq < 56)      { b = 6; off = pq - 48; }
        else if (pq < 72) { b = 7; off = pq - 56; }
        else              { b = 8; off = pq - 72; }
    }
    int ls = b / 3, lsp = b % 3, w = 2 * lsp + 1;
    if (off >= (2 * ls + 1) * w) return false;
    s  = ls * ls + off / w;
    sp = lsp * lsp + off % w;
    return true;
}

// ---- P1: A[81][380], YT[25][380], V[5][9][32] — embarrassingly parallel
__global__ void precompAux(const float* __restrict__ Wx, const float* __restrict__ Wy,
                           const float* __restrict__ Wz, const float* __restrict__ Yin,
                           const float* __restrict__ Yout, const float* __restrict__ wq,
                           float* __restrict__ A, float* __restrict__ YT,
                           float* __restrict__ V) {
    int idx = blockIdx.x * blockDim.x + threadIdx.x;
    if (idx < 81 * GG) {
        int p = idx / GG, g = idx % GG, s = p / 9, sp = p % 9;
        A[idx] = wq[g] * Yin[g * 9 + s] * Yin[g * 9 + sp];
    } else if (idx < 81 * GG + 25 * GG) {
        int i = idx - 81 * GG, t = i / GG, g = i % GG;
        YT[i] = Yout[g * 25 + t];
    } else if (idx < 81 * GG + 25 * GG + 1440) {
        int i = idx - 81 * GG - 25 * GG;
        int lt = i / 288, r = i % 288, b = r / 32, d = r % 32;
        int ls = b / 3, lsp = b % 3;
        float acc = 0.f;
        for (int c = 0; c < 32; ++c)
            acc = fmaf(Wx[ls * 32 + c] * Wy[lsp * 32 + c],
                       Wz[lt * 1024 + c * 32 + d], acc);
        V[i] = acc;
    }
}

// ---- P2: T[t][100] block-padded, via float4 dots
__global__ void precompT100(const float* __restrict__ A, const float* __restrict__ YT,
                            float* __restrict__ Tg) {
    int idx = blockIdx.x * blockDim.x + threadIdx.x;
    if (idx >= 25 * 100) return;
    int t = idx / 100, pq = idx % 100;
    float acc = 0.f;
    int s, sp;
    if (decode2(pq, s, sp)) {
        int p = s * 9 + sp;
        const float4* a4 = (const float4*)(A + p * GG);
        const float4* y4 = (const float4*)(YT + t * GG);
#pragma unroll 5
        for (int k = 0; k < GG / 4; ++k) {
            float4 a = a4[k], yv = y4[k];
            acc = fmaf(a.x, yv.x, acc); acc = fmaf(a.y, yv.y, acc);
            acc = fmaf(a.z, yv.z, acc); acc = fmaf(a.w, yv.w, acc);
        }
    }
    Tg[idx] = acc;
}

// ---- main: 4 samples/block, 512 blocks, 256 threads.
// LDS floats (58.56 KB):
//   Zout [0, 9600)     — phase-B output, overlays ONLY dead phase-A scratch:
//     xs [0,108) | ys [108,216) | Ps [216,1416) | Ts [1416,3916)
//   Z    [9600, 13200) — 12 rows * 300
//   Vs   [13200, 14640)
__global__ __launch_bounds__(256) void gaunt_main(const float* __restrict__ x,
                                                  const float* __restrict__ y,
                                                  const float* __restrict__ Tg,
                                                  const float* __restrict__ Vg,
                                                  float* __restrict__ out) {
    __shared__ __align__(16) float smem[14640];
    float* xs   = smem;            // 108
    float* ys   = smem + 108;      // 108
    float* Ps   = smem + 216;      // 12*100
    float* Ts   = smem + 1416;     // 25*100
    float* Z    = smem + 9600;     // 12*300
    float* Vs   = smem + 13200;    // 1440
    float* Zout = smem;            // 9600, phase B only

    const int tid = threadIdx.x;
    const int n0 = blockIdx.x * 4;

    if (tid < 108)      xs[tid]       = x[n0 * 27 + tid];
    else if (tid < 216) ys[tid - 108] = y[n0 * 27 + tid - 108];
    for (int i = tid; i < 625; i += 256)            // Ts: 2500 floats
        ((float4*)Ts)[i] = ((const float4*)Tg)[i];
    for (int i = tid; i < 360; i += 256)            // Vs: 1440 floats (strided!)
        ((float4*)Vs)[i] = ((const float4*)Vg)[i];
    __syncthreads();

    // P[row][100], pads zero
    for (int idx = tid; idx < 1200; idx += 256) {
        int row = idx / 100, pq = idx % 100;
        float v = 0.f;
        int s, sp;
        if (decode2(pq, s, sp)) {
            int ni = row / 3, vv = row % 3;
            int a = (vv == 0) ? 1 : ((vv == 1) ? 2 : 0);
            int b = (vv == 0) ? 2 : ((vv == 1) ? 0 : 1);
            v = xs[ni * 27 + a * 9 + s] * ys[ni * 27 + b * 9 + sp]
              - xs[ni * 27 + b * 9 + s] * ys[ni * 27 + a * 9 + sp];
        }
        Ps[idx] = v;
    }
    __syncthreads();

    // Stage A: 300 (t,row) pairs; 25 f4-chunk dots -> 9 block sums
#define DOT4(c, accv) { float4 pv = P4[c], tv = T4[c];                      \
        accv = fmaf(pv.x, tv.x, accv); accv = fmaf(pv.y, tv.y, accv);       \
        accv = fmaf(pv.z, tv.z, accv); accv = fmaf(pv.w, tv.w, accv); }
    for (int pair = tid; pair < 300; pair += 256) {
        int t = pair / 12, row = pair % 12;
        const float4* P4 = (const float4*)(Ps + row * 100);
        const float4* T4 = (const float4*)(Ts + t * 100);
        float a0 = 0.f, a1 = 0.f, a2 = 0.f, a3 = 0.f, a4 = 0.f,
              a5 = 0.f, a6 = 0.f, a7 = 0.f, a8 = 0.f;
        DOT4(0, a0)
        DOT4(1, a1)
        DOT4(2, a2)  DOT4(3, a2)
        DOT4(4, a3)
        DOT4(5, a4)  DOT4(6, a4)  DOT4(7, a4)
        DOT4(8, a5)  DOT4(9, a5)  DOT4(10, a5) DOT4(11, a5)
        DOT4(12, a6) DOT4(13, a6)
        DOT4(14, a7) DOT4(15, a7) DOT4(16, a7) DOT4(17, a7)
        DOT4(18, a8) DOT4(19, a8) DOT4(20, a8) DOT4(21, a8)
        DOT4(22, a8) DOT4(23, a8) DOT4(24, a8)
        float* zp = Z + row * 300 + t * 12;
        *(float4*)zp       = make_float4(a0, a1, a2, a3);
        *(float4*)(zp + 4) = make_float4(a4, a5, a6, a7);
        zp[8] = a8;
    }
#undef DOT4
    __syncthreads();

    // Stage B: thread = (d = tid&31, g = tid>>5); rows {g} and {8+g if g<4}.
    // V hoisted per lt (9 regs, stride-32 conflict-free); Z read as 2xf4+1.
    {
        const int d = tid & 31, g = tid >> 5;
#pragma unroll
        for (int rsel = 0; rsel < 2; ++rsel) {
            const int row = rsel ? (8 + g) : g;
            if (rsel && g >= 4) break;
            const int zo = (row / 3) * 2400 + d * 75 + (row % 3) * 25;
            const float* zrow = Z + row * 300;
#pragma unroll
            for (int lt = 0; lt < 5; ++lt) {
                const float* vb = Vs + lt * 288 + d;
                const float v0 = vb[0],   v1 = vb[32],  v2 = vb[64],
                            v3 = vb[96],  v4 = vb[128], v5 = vb[160],
                            v6 = vb[192], v7 = vb[224], v8 = vb[256];
                const int t0 = lt * lt, t1 = (lt + 1) * (lt + 1);
#pragma unroll
                for (int t = t0; t < t1; ++t) {
                    const float* zp = zrow + t * 12;
                    float4 za = *(const float4*)zp;
                    float4 zb = *(const float4*)(zp + 4);
                    float acc = zp[8] * v8;
                    acc = fmaf(za.x, v0, acc); acc = fmaf(za.y, v1, acc);
                    acc = fmaf(za.z, v2, acc); acc = fmaf(za.w, v3, acc);
                    acc = fmaf(zb.x, v4, acc); acc = fmaf(zb.y, v5, acc);
                    acc = fmaf(zb.z, v6, acc); acc = fmaf(zb.w, v7, acc);
                    Zout[zo + t] = acc;
                }
            }
        }
    }
    __syncthreads();

    // coalesced copy-out: 9600 floats = 2400 float4, contiguous
    float4* og = (float4*)(out + (size_t)n0 * 2400);
    const float4* zo4 = (const float4*)Zout;
    for (int i = tid; i < 2400; i += 256) og[i] = zo4[i];
}

extern "C" void kernel_launch(void* const* d_in, const int* in_sizes, int n_in,
                              void* d_out, int out_size, void* d_ws, size_t ws_size,
                              hipStream_t stream) {
    const float* x    = (const float*)d_in[0];
    const float* y    = (const float*)d_in[1];
    const float* Wx   = (const float*)d_in[2];
    const float* Wy   = (const float*)d_in[3];
    const float* Wz   = (const float*)d_in[4];
    const float* Yin  = (const float*)d_in[5];
    const float* Yout = (const float*)d_in[6];
    const float* wq   = (const float*)d_in[7];
    float* out = (float*)d_out;

    float* A  = (float*)d_ws;        // 81*380 = 30780
    float* YT = A + 81 * GG;         // 25*380 = 9500
    float* Vg = YT + 25 * GG;        // 1440
    float* Tg = Vg + 1440;           // 25*100 = 2500

    int auxTotal = 81 * GG + 25 * GG + 1440;   // 41720
    precompAux<<<(auxTotal + 255) / 256, 256, 0, stream>>>(Wx, Wy, Wz, Yin, Yout, wq,
                                                           A, YT, Vg);
    precompT100<<<(25 * 100 + 255) / 256, 256, 0, stream>>>(A, YT, Tg);
    gaunt_main<<<512, 256, 0, stream>>>(x, y, Tg, Vg, out);
}

// Round 9
// 29.083 us; speedup vs baseline: 3.8348x; 1.1571x over previous
//
#include <hip/hip_runtime.h>

// VectorGauntTensorProduct — factored algebraic collapse, 2-launch structure.
//
// T[t,pq]  = sum_g wq[g] Yin[g,s] Yin[g,sp] Yout[g,t]       (25x100, block-padded)
// V[lt,b,d]= sum_c Wx[ls,c] Wy[lsp,c] Wz[lt,c,d]            (b = ls*3+lsp, 5x9x32)
// P[row,pq]= x[n,a,s] y[n,b,sp] - x[n,b,s] y[n,a,sp]        (row = ni*3+v)
// Z[row,t,b] = sum_{pq in block b} P[row,pq] T[t,pq]        (f4 chunk ranges)
// out[n,d,v,t] = sum_b Z[row,t,b] V[l(t),b,d]
//
// Padded block layout: block b = ls*3+lsp, real sizes {1,3,5,3,9,15,5,15,25}
// padded to /4: {4,4,8,4,12,16,8,16,28}, starts {0,4,8,16,20,32,48,56,72}, tot 100.
// Pads are 0.0 in BOTH T and P -> contribute nothing.
//
// BUG HISTORY: r4 Zout/Vs overlay race; r4-r6 `if(tid<360)` staging with 256
// threads left Vs[1024:1440) unstaged. Staging loops are STRIDED; no overlays.

#define GG 380

// decode padded index pq (<100) -> (s, sp); false if pad slot
__device__ __forceinline__ bool decode2(int pq, int& s, int& sp) {
    int b, off;
    if (pq < 16) {
        if (pq < 4)       { b = 0; off = pq; }
        else if (pq < 8)  { b = 1; off = pq - 4; }
        else              { b = 2; off = pq - 8; }
    } else if (pq < 48) {
        if (pq < 20)      { b = 3; off = pq - 16; }
        else if (pq < 32) { b = 4; off = pq - 20; }
        else              { b = 5; off = pq - 32; }
    } else {
        if (pq < 56)      { b = 6; off = pq - 48; }
        else if (pq < 72) { b = 7; off = pq - 56; }
        else              { b = 8; off = pq - 72; }
    }
    int ls = b / 3, lsp = b % 3, w = 2 * lsp + 1;
    if (off >= (2 * ls + 1) * w) return false;
    s  = ls * ls + off / w;
    sp = lsp * lsp + off % w;
    return true;
}

// ---- precomp (single kernel): T wave-per-entry + V
// blocks [0,625): 4 waves each, wave W = bid*4 + tid/64 computes T entry W
// blocks [625,631): V[5][9][32] = 1440 entries
__global__ __launch_bounds__(256) void precomp(const float* __restrict__ Wx,
                                               const float* __restrict__ Wy,
                                               const float* __restrict__ Wz,
                                               const float* __restrict__ Yin,
                                               const float* __restrict__ Yout,
                                               const float* __restrict__ wq,
                                               float* __restrict__ Tg,
                                               float* __restrict__ Vg) {
    int bid = blockIdx.x;
    if (bid < 625) {
        int W = bid * 4 + (threadIdx.x >> 6);     // 0..2499, = t*100 + pq
        int lane = threadIdx.x & 63;
        int t = W / 100, pq = W % 100;
        int s, sp;
        float acc = 0.f;
        if (decode2(pq, s, sp)) {
#pragma unroll
            for (int i = 0; i < 6; ++i) {
                int g = lane + 64 * i;
                if (g < GG)
                    acc = fmaf(wq[g] * Yin[g * 9 + s],
                               Yin[g * 9 + sp] * Yout[g * 25 + t], acc);
            }
        }
#pragma unroll
        for (int m = 32; m; m >>= 1) acc += __shfl_xor(acc, m, 64);
        if (lane == 0) Tg[W] = acc;               // pads write 0
    } else {
        int idx = (bid - 625) * 256 + threadIdx.x;
        if (idx < 1440) {
            int lt = idx / 288, r = idx % 288, b = r / 32, d = r % 32;
            int ls = b / 3, lsp = b % 3;
            float acc = 0.f;
            for (int c = 0; c < 32; ++c)
                acc = fmaf(Wx[ls * 32 + c] * Wy[lsp * 32 + c],
                           Wz[lt * 1024 + c * 32 + d], acc);
            Vg[idx] = acc;
        }
    }
}

// ---- main: 2 samples/block, 1024 blocks, 256 threads, LDS 25.8 KB (no overlays).
// LDS floats: xs[0,54) ys[54,108) Ps[108,708) Ts[708,3208) Vs[3208,4648)
//             Z[4648,6448)   — total 6448 floats, all disjoint, all f4-aligned.
__global__ __launch_bounds__(256) void gaunt_main(const float* __restrict__ x,
                                                  const float* __restrict__ y,
                                                  const float* __restrict__ Tg,
                                                  const float* __restrict__ Vg,
                                                  float* __restrict__ out) {
    __shared__ __align__(16) float smem[6448];
    float* xs = smem;            // 54
    float* ys = smem + 54;       // 54
    float* Ps = smem + 108;      // 6*100
    float* Ts = smem + 708;      // 25*100
    float* Vs = smem + 3208;     // 1440
    float* Z  = smem + 4648;     // 6*300

    const int tid = threadIdx.x;
    const int n0 = blockIdx.x * 2;

    if (tid < 54)       xs[tid]      = x[n0 * 27 + tid];
    else if (tid < 108) ys[tid - 54] = y[n0 * 27 + tid - 54];
    for (int i = tid; i < 625; i += 256)            // Ts: 2500 floats
        ((float4*)Ts)[i] = ((const float4*)Tg)[i];
    for (int i = tid; i < 360; i += 256)            // Vs: 1440 floats (strided)
        ((float4*)Vs)[i] = ((const float4*)Vg)[i];
    __syncthreads();

    // P[row][100], pads zero
    for (int idx = tid; idx < 600; idx += 256) {
        int row = idx / 100, pq = idx % 100;
        float v = 0.f;
        int s, sp;
        if (decode2(pq, s, sp)) {
            int ni = row / 3, vv = row % 3;
            int a = (vv == 0) ? 1 : ((vv == 1) ? 2 : 0);
            int b = (vv == 0) ? 2 : ((vv == 1) ? 0 : 1);
            v = xs[ni * 27 + a * 9 + s] * ys[ni * 27 + b * 9 + sp]
              - xs[ni * 27 + b * 9 + s] * ys[ni * 27 + a * 9 + sp];
        }
        Ps[idx] = v;
    }
    __syncthreads();

    // Stage A: 150 (t,row) pairs; 25 f4-chunk dots -> 9 block sums
#define DOT4(c, accv) { float4 pv = P4[c], tv = T4[c];                      \
        accv = fmaf(pv.x, tv.x, accv); accv = fmaf(pv.y, tv.y, accv);       \
        accv = fmaf(pv.z, tv.z, accv); accv = fmaf(pv.w, tv.w, accv); }
    if (tid < 150) {
        int t = tid / 6, row = tid % 6;
        const float4* P4 = (const float4*)(Ps + row * 100);
        const float4* T4 = (const float4*)(Ts + t * 100);
        float a0 = 0.f, a1 = 0.f, a2 = 0.f, a3 = 0.f, a4 = 0.f,
              a5 = 0.f, a6 = 0.f, a7 = 0.f, a8 = 0.f;
        DOT4(0, a0)
        DOT4(1, a1)
        DOT4(2, a2)  DOT4(3, a2)
        DOT4(4, a3)
        DOT4(5, a4)  DOT4(6, a4)  DOT4(7, a4)
        DOT4(8, a5)  DOT4(9, a5)  DOT4(10, a5) DOT4(11, a5)
        DOT4(12, a6) DOT4(13, a6)
        DOT4(14, a7) DOT4(15, a7) DOT4(16, a7) DOT4(17, a7)
        DOT4(18, a8) DOT4(19, a8) DOT4(20, a8) DOT4(21, a8)
        DOT4(22, a8) DOT4(23, a8) DOT4(24, a8)
        float* zp = Z + row * 300 + t * 12;
        *(float4*)zp       = make_float4(a0, a1, a2, a3);
        *(float4*)(zp + 4) = make_float4(a4, a5, a6, a7);
        zp[8] = a8;
    }
#undef DOT4
    __syncthreads();

    // Stage B: thread = (d = tid&31, g = tid>>5); g<6 -> row g.
    // Direct global stores: 25 consecutive floats per (row,d) — merged wide stores.
    {
        const int d = tid & 31, g = tid >> 5;
        if (g < 6) {
            const int row = g;
            const int ob = (n0 + row / 3) * 2400 + d * 75 + (row % 3) * 25;
            const float* zrow = Z + row * 300;
#pragma unroll
            for (int lt = 0; lt < 5; ++lt) {
                const float* vb = Vs + lt * 288 + d;
                const float v0 = vb[0],   v1 = vb[32],  v2 = vb[64],
                            v3 = vb[96],  v4 = vb[128], v5 = vb[160],
                            v6 = vb[192], v7 = vb[224], v8 = vb[256];
                const int t0 = lt * lt, t1 = (lt + 1) * (lt + 1);
#pragma unroll
                for (int t = t0; t < t1; ++t) {
                    const float* zp = zrow + t * 12;
                    float4 za = *(const float4*)zp;
                    float4 zb = *(const float4*)(zp + 4);
                    float acc = zp[8] * v8;
                    acc = fmaf(za.x, v0, acc); acc = fmaf(za.y, v1, acc);
                    acc = fmaf(za.z, v2, acc); acc = fmaf(za.w, v3, acc);
                    acc = fmaf(zb.x, v4, acc); acc = fmaf(zb.y, v5, acc);
                    acc = fmaf(zb.z, v6, acc); acc = fmaf(zb.w, v7, acc);
                    out[ob + t] = acc;
                }
            }
        }
    }
}

extern "C" void kernel_launch(void* const* d_in, const int* in_sizes, int n_in,
                              void* d_out, int out_size, void* d_ws, size_t ws_size,
                              hipStream_t stream) {
    const float* x    = (const float*)d_in[0];
    const float* y    = (const float*)d_in[1];
    const float* Wx   = (const float*)d_in[2];
    const float* Wy   = (const float*)d_in[3];
    const float* Wz   = (const float*)d_in[4];
    const float* Yin  = (const float*)d_in[5];
    const float* Yout = (const float*)d_in[6];
    const float* wq   = (const float*)d_in[7];
    float* out = (float*)d_out;

    float* Tg = (float*)d_ws;        // 25*100 = 2500 floats
    float* Vg = Tg + 2500;           // 1440 floats (offset 10000B, 16B-aligned)

    precomp<<<631, 256, 0, stream>>>(Wx, Wy, Wz, Yin, Yout, wq, Tg, Vg);
    gaunt_main<<<1024, 256, 0, stream>>>(x, y, Tg, Vg, out);
}

// Round 10
// 24.595 us; speedup vs baseline: 4.5346x; 1.1825x over previous
//
#include <hip/hip_runtime.h>

// VectorGauntTensorProduct — factored algebraic collapse, 2-launch structure.
// r10 = r9 + stage-B LDS transpose (Zout) + coalesced float4 copy-out.
//
// T[t,pq]  = sum_g wq[g] Yin[g,s] Yin[g,sp] Yout[g,t]       (25x100, block-padded)
// V[lt,b,d]= sum_c Wx[ls,c] Wy[lsp,c] Wz[lt,c,d]            (b = ls*3+lsp, 5x9x32)
// P[row,pq]= x[n,a,s] y[n,b,sp] - x[n,b,s] y[n,a,sp]        (row = ni*3+v)
// Z[row,t,b] = sum_{pq in block b} P[row,pq] T[t,pq]        (f4 chunk ranges)
// out[n,d,v,t] = sum_b Z[row,t,b] V[l(t),b,d]
//
// Padded block layout: block b = ls*3+lsp, real sizes {1,3,5,3,9,15,5,15,25}
// padded to /4: {4,4,8,4,12,16,8,16,28}, starts {0,4,8,16,20,32,48,56,72}, tot 100.
// Pads are 0.0 in BOTH T and P -> contribute nothing.
//
// BUG HISTORY: r4 Zout/Vs overlay race; r4-r6 `if(tid<360)` staging with 256
// threads left Vs[1024:1440) unstaged. Staging loops are STRIDED; no overlays.
// r9 lesson candidate: direct scatter stores (stride-300B per lane) amplify L2
// write-sector traffic ~16x -> this round stages via Zout + coalesced copy-out.

#define GG 380

// decode padded index pq (<100) -> (s, sp); false if pad slot
__device__ __forceinline__ bool decode2(int pq, int& s, int& sp) {
    int b, off;
    if (pq < 16) {
        if (pq < 4)       { b = 0; off = pq; }
        else if (pq < 8)  { b = 1; off = pq - 4; }
        else              { b = 2; off = pq - 8; }
    } else if (pq < 48) {
        if (pq < 20)      { b = 3; off = pq - 16; }
        else if (pq < 32) { b = 4; off = pq - 20; }
        else              { b = 5; off = pq - 32; }
    } else {
        if (pq < 56)      { b = 6; off = pq - 48; }
        else if (pq < 72) { b = 7; off = pq - 56; }
        else              { b = 8; off = pq - 72; }
    }
    int ls = b / 3, lsp = b % 3, w = 2 * lsp + 1;
    if (off >= (2 * ls + 1) * w) return false;
    s  = ls * ls + off / w;
    sp = lsp * lsp + off % w;
    return true;
}

// ---- precomp (single kernel): T wave-per-entry + V  (r9-proven, unchanged)
__global__ __launch_bounds__(256) void precomp(const float* __restrict__ Wx,
                                               const float* __restrict__ Wy,
                                               const float* __restrict__ Wz,
                                               const float* __restrict__ Yin,
                                               const float* __restrict__ Yout,
                                               const float* __restrict__ wq,
                                               float* __restrict__ Tg,
                                               float* __restrict__ Vg) {
    int bid = blockIdx.x;
    if (bid < 625) {
        int W = bid * 4 + (threadIdx.x >> 6);     // 0..2499, = t*100 + pq
        int lane = threadIdx.x & 63;
        int t = W / 100, pq = W % 100;
        int s, sp;
        float acc = 0.f;
        if (decode2(pq, s, sp)) {
#pragma unroll
            for (int i = 0; i < 6; ++i) {
                int g = lane + 64 * i;
                if (g < GG)
                    acc = fmaf(wq[g] * Yin[g * 9 + s],
                               Yin[g * 9 + sp] * Yout[g * 25 + t], acc);
            }
        }
#pragma unroll
        for (int m = 32; m; m >>= 1) acc += __shfl_xor(acc, m, 64);
        if (lane == 0) Tg[W] = acc;               // pads write 0
    } else {
        int idx = (bid - 625) * 256 + threadIdx.x;
        if (idx < 1440) {
            int lt = idx / 288, r = idx % 288, b = r / 32, d = r % 32;
            int ls = b / 3, lsp = b % 3;
            float acc = 0.f;
            for (int c = 0; c < 32; ++c)
                acc = fmaf(Wx[ls * 32 + c] * Wy[lsp * 32 + c],
                           Wz[lt * 1024 + c * 32 + d], acc);
            Vg[idx] = acc;
        }
    }
}

// ---- main: 2 samples/block, 1024 blocks, 256 threads, LDS 45.0 KB, no overlays.
// LDS floats: xs[0,54) ys[54,108) Ps[108,708) Ts[708,3208) Vs[3208,4648)
//             Z[4648,6448) Zout[6448,11248)  — all disjoint, f4-aligned.
__global__ __launch_bounds__(256) void gaunt_main(const float* __restrict__ x,
                                                  const float* __restrict__ y,
                                                  const float* __restrict__ Tg,
                                                  const float* __restrict__ Vg,
                                                  float* __restrict__ out) {
    __shared__ __align__(16) float smem[11248];
    float* xs   = smem;            // 54
    float* ys   = smem + 54;       // 54
    float* Ps   = smem + 108;      // 6*100
    float* Ts   = smem + 708;      // 25*100
    float* Vs   = smem + 3208;     // 1440
    float* Z    = smem + 4648;     // 6*300
    float* Zout = smem + 6448;     // 4800

    const int tid = threadIdx.x;
    const int n0 = blockIdx.x * 2;

    if (tid < 54)       xs[tid]      = x[n0 * 27 + tid];
    else if (tid < 108) ys[tid - 54] = y[n0 * 27 + tid - 54];
    for (int i = tid; i < 625; i += 256)            // Ts: 2500 floats
        ((float4*)Ts)[i] = ((const float4*)Tg)[i];
    for (int i = tid; i < 360; i += 256)            // Vs: 1440 floats (strided)
        ((float4*)Vs)[i] = ((const float4*)Vg)[i];
    __syncthreads();

    // P[row][100], pads zero
    for (int idx = tid; idx < 600; idx += 256) {
        int row = idx / 100, pq = idx % 100;
        float v = 0.f;
        int s, sp;
        if (decode2(pq, s, sp)) {
            int ni = row / 3, vv = row % 3;
            int a = (vv == 0) ? 1 : ((vv == 1) ? 2 : 0);
            int b = (vv == 0) ? 2 : ((vv == 1) ? 0 : 1);
            v = xs[ni * 27 + a * 9 + s] * ys[ni * 27 + b * 9 + sp]
              - xs[ni * 27 + b * 9 + s] * ys[ni * 27 + a * 9 + sp];
        }
        Ps[idx] = v;
    }
    __syncthreads();

    // Stage A: 150 (t,row) pairs; 25 f4-chunk dots -> 9 block sums
#define DOT4(c, accv) { float4 pv = P4[c], tv = T4[c];                      \
        accv = fmaf(pv.x, tv.x, accv); accv = fmaf(pv.y, tv.y, accv);       \
        accv = fmaf(pv.z, tv.z, accv); accv = fmaf(pv.w, tv.w, accv); }
    if (tid < 150) {
        int t = tid / 6, row = tid % 6;
        const float4* P4 = (const float4*)(Ps + row * 100);
        const float4* T4 = (const float4*)(Ts + t * 100);
        float a0 = 0.f, a1 = 0.f, a2 = 0.f, a3 = 0.f, a4 = 0.f,
              a5 = 0.f, a6 = 0.f, a7 = 0.f, a8 = 0.f;
        DOT4(0, a0)
        DOT4(1, a1)
        DOT4(2, a2)  DOT4(3, a2)
        DOT4(4, a3)
        DOT4(5, a4)  DOT4(6, a4)  DOT4(7, a4)
        DOT4(8, a5)  DOT4(9, a5)  DOT4(10, a5) DOT4(11, a5)
        DOT4(12, a6) DOT4(13, a6)
        DOT4(14, a7) DOT4(15, a7) DOT4(16, a7) DOT4(17, a7)
        DOT4(18, a8) DOT4(19, a8) DOT4(20, a8) DOT4(21, a8)
        DOT4(22, a8) DOT4(23, a8) DOT4(24, a8)
        float* zp = Z + row * 300 + t * 12;
        *(float4*)zp       = make_float4(a0, a1, a2, a3);
        *(float4*)(zp + 4) = make_float4(a4, a5, a6, a7);
        zp[8] = a8;
    }
#undef DOT4
    __syncthreads();

    // Stage B: thread = (d = tid&31, g = tid>>5); g<6 -> row g.
    // Writes to Zout (LDS transpose): addr = local_n*2400 + d*75 + v*25 + t
    // -> bank (11d+t)%32, distinct per lane: conflict-free.
    {
        const int d = tid & 31, g = tid >> 5;
        if (g < 6) {
            const int row = g;
            const int zo = (row / 3) * 2400 + d * 75 + (row % 3) * 25;
            const float* zrow = Z + row * 300;
#pragma unroll
            for (int lt = 0; lt < 5; ++lt) {
                const float* vb = Vs + lt * 288 + d;
                const float v0 = vb[0],   v1 = vb[32],  v2 = vb[64],
                            v3 = vb[96],  v4 = vb[128], v5 = vb[160],
                            v6 = vb[192], v7 = vb[224], v8 = vb[256];
                const int t0 = lt * lt, t1 = (lt + 1) * (lt + 1);
#pragma unroll
                for (int t = t0; t < t1; ++t) {
                    const float* zp = zrow + t * 12;
                    float4 za = *(const float4*)zp;
                    float4 zb = *(const float4*)(zp + 4);
                    float acc = zp[8] * v8;
                    acc = fmaf(za.x, v0, acc); acc = fmaf(za.y, v1, acc);
                    acc = fmaf(za.z, v2, acc); acc = fmaf(za.w, v3, acc);
                    acc = fmaf(zb.x, v4, acc); acc = fmaf(zb.y, v5, acc);
                    acc = fmaf(zb.z, v6, acc); acc = fmaf(zb.w, v7, acc);
                    Zout[zo + t] = acc;
                }
            }
        }
    }
    __syncthreads();

    // coalesced copy-out: 4800 floats = 1200 float4, contiguous per block
    float4* og = (float4*)(out + (size_t)n0 * 2400);
    const float4* zo4 = (const float4*)Zout;
    for (int i = tid; i < 1200; i += 256) og[i] = zo4[i];
}

extern "C" void kernel_launch(void* const* d_in, const int* in_sizes, int n_in,
                              void* d_out, int out_size, void* d_ws, size_t ws_size,
                              hipStream_t stream) {
    const float* x    = (const float*)d_in[0];
    const float* y    = (const float*)d_in[1];
    const float* Wx   = (const float*)d_in[2];
    const float* Wy   = (const float*)d_in[3];
    const float* Wz   = (const float*)d_in[4];
    const float* Yin  = (const float*)d_in[5];
    const float* Yout = (const float*)d_in[6];
    const float* wq   = (const float*)d_in[7];
    float* out = (float*)d_out;

    float* Tg = (float*)d_ws;        // 25*100 = 2500 floats
    float* Vg = Tg + 2500;           // 1440 floats (offset 10000B, 16B-aligned)

    precomp<<<631, 256, 0, stream>>>(Wx, Wy, Wz, Yin, Yout, wq, Tg, Vg);
    gaunt_main<<<1024, 256, 0, stream>>>(x, y, Tg, Vg, out);
}

// Round 11
// 20.999 us; speedup vs baseline: 5.3111x; 1.1713x over previous
//
#include <hip/hip_runtime.h>

// VectorGauntTensorProduct — factored algebraic collapse, 2-launch structure.
// r11 = r10 with LDS shrunk to 35.4 KB: Zout overlays Ts (dead after stage A)
// -> 4 blocks/CU resident, the whole 1024-block grid runs in ONE latency round.
//
// T[t,pq]  = sum_g wq[g] Yin[g,s] Yin[g,sp] Yout[g,t]       (25x100, block-padded)
// V[lt,b,d]= sum_c Wx[ls,c] Wy[lsp,c] Wz[lt,c,d]            (b = ls*3+lsp, 5x9x32)
// P[row,pq]= x[n,a,s] y[n,b,sp] - x[n,b,s] y[n,a,sp]        (row = ni*3+v)
// Z[row,t,b] = sum_{pq in block b} P[row,pq] T[t,pq]        (f4 chunk ranges)
// out[n,d,v,t] = sum_b Z[row,t,b] V[l(t),b,d]
//
// Padded block layout: block b = ls*3+lsp, real sizes {1,3,5,3,9,15,5,15,25}
// padded to /4: {4,4,8,4,12,16,8,16,28}, starts {0,4,8,16,20,32,48,56,72}, tot 100.
// Pads are 0.0 in BOTH T and P -> contribute nothing.
//
// BUG HISTORY: r4 Zout/Vs overlay race; r4-r6 `if(tid<360)` staging with 256
// threads left Vs[1024:1440) unstaged. Staging loops are STRIDED. Overlay rule:
// Zout may only overlay buffers DEAD before the post-stage-A barrier (Ts only).
// r9->r10 lesson: direct scatter stores (300B-stride lanes) amplify L2 write
// sectors ~16x; always stage output through LDS and store coalesced float4.

#define GG 380

// decode padded index pq (<100) -> (s, sp); false if pad slot
__device__ __forceinline__ bool decode2(int pq, int& s, int& sp) {
    int b, off;
    if (pq < 16) {
        if (pq < 4)       { b = 0; off = pq; }
        else if (pq < 8)  { b = 1; off = pq - 4; }
        else              { b = 2; off = pq - 8; }
    } else if (pq < 48) {
        if (pq < 20)      { b = 3; off = pq - 16; }
        else if (pq < 32) { b = 4; off = pq - 20; }
        else              { b = 5; off = pq - 32; }
    } else {
        if (pq < 56)      { b = 6; off = pq - 48; }
        else if (pq < 72) { b = 7; off = pq - 56; }
        else              { b = 8; off = pq - 72; }
    }
    int ls = b / 3, lsp = b % 3, w = 2 * lsp + 1;
    if (off >= (2 * ls + 1) * w) return false;
    s  = ls * ls + off / w;
    sp = lsp * lsp + off % w;
    return true;
}

// ---- precomp (single kernel): T wave-per-entry + V  (r9-proven, unchanged)
__global__ __launch_bounds__(256) void precomp(const float* __restrict__ Wx,
                                               const float* __restrict__ Wy,
                                               const float* __restrict__ Wz,
                                               const float* __restrict__ Yin,
                                               const float* __restrict__ Yout,
                                               const float* __restrict__ wq,
                                               float* __restrict__ Tg,
                                               float* __restrict__ Vg) {
    int bid = blockIdx.x;
    if (bid < 625) {
        int W = bid * 4 + (threadIdx.x >> 6);     // 0..2499, = t*100 + pq
        int lane = threadIdx.x & 63;
        int t = W / 100, pq = W % 100;
        int s, sp;
        float acc = 0.f;
        if (decode2(pq, s, sp)) {
#pragma unroll
            for (int i = 0; i < 6; ++i) {
                int g = lane + 64 * i;
                if (g < GG)
                    acc = fmaf(wq[g] * Yin[g * 9 + s],
                               Yin[g * 9 + sp] * Yout[g * 25 + t], acc);
            }
        }
#pragma unroll
        for (int m = 32; m; m >>= 1) acc += __shfl_xor(acc, m, 64);
        if (lane == 0) Tg[W] = acc;               // pads write 0
    } else {
        int idx = (bid - 625) * 256 + threadIdx.x;
        if (idx < 1440) {
            int lt = idx / 288, r = idx % 288, b = r / 32, d = r % 32;
            int ls = b / 3, lsp = b % 3;
            float acc = 0.f;
            for (int c = 0; c < 32; ++c)
                acc = fmaf(Wx[ls * 32 + c] * Wy[lsp * 32 + c],
                           Wz[lt * 1024 + c * 32 + d], acc);
            Vg[idx] = acc;
        }
    }
}

// ---- main: 2 samples/block, 1024 blocks, 256 threads, LDS 35.4 KB.
// LDS floats: xs[0,108)* ys[108,216)* Ps[216,816) Vs[816,2256) Z[2256,4056)
//             Ts[4056,6556) | Zout[4056,8856) overlays Ts(dead)+fresh space.
//             (*xs/ys use only first 54 each; rounded for alignment)
__global__ __launch_bounds__(256) void gaunt_main(const float* __restrict__ x,
                                                  const float* __restrict__ y,
                                                  const float* __restrict__ Tg,
                                                  const float* __restrict__ Vg,
                                                  float* __restrict__ out) {
    __shared__ __align__(16) float smem[8856];
    float* xs   = smem;            // 54 used
    float* ys   = smem + 108;      // 54 used
    float* Ps   = smem + 216;      // 6*100
    float* Vs   = smem + 816;      // 1440
    float* Z    = smem + 2256;     // 6*300
    float* Ts   = smem + 4056;     // 25*100 (dead after stage A)
    float* Zout = smem + 4056;     // 4800 (phase B + copy-out only)

    const int tid = threadIdx.x;
    const int n0 = blockIdx.x * 2;

    if (tid < 54)       xs[tid]      = x[n0 * 27 + tid];
    else if (tid < 108) ys[tid - 54] = y[n0 * 27 + tid - 54];
    for (int i = tid; i < 625; i += 256)            // Ts: 2500 floats
        ((float4*)Ts)[i] = ((const float4*)Tg)[i];
    for (int i = tid; i < 360; i += 256)            // Vs: 1440 floats (strided)
        ((float4*)Vs)[i] = ((const float4*)Vg)[i];
    __syncthreads();

    // P[row][100], pads zero
    for (int idx = tid; idx < 600; idx += 256) {
        int row = idx / 100, pq = idx % 100;
        float v = 0.f;
        int s, sp;
        if (decode2(pq, s, sp)) {
            int ni = row / 3, vv = row % 3;
            int a = (vv == 0) ? 1 : ((vv == 1) ? 2 : 0);
            int b = (vv == 0) ? 2 : ((vv == 1) ? 0 : 1);
            v = xs[ni * 27 + a * 9 + s] * ys[ni * 27 + b * 9 + sp]
              - xs[ni * 27 + b * 9 + s] * ys[ni * 27 + a * 9 + sp];
        }
        Ps[idx] = v;
    }
    __syncthreads();

    // Stage A: 150 (t,row) pairs; 25 f4-chunk dots -> 9 block sums
#define DOT4(c, accv) { float4 pv = P4[c], tv = T4[c];                      \
        accv = fmaf(pv.x, tv.x, accv); accv = fmaf(pv.y, tv.y, accv);       \
        accv = fmaf(pv.z, tv.z, accv); accv = fmaf(pv.w, tv.w, accv); }
    if (tid < 150) {
        int t = tid / 6, row = tid % 6;
        const float4* P4 = (const float4*)(Ps + row * 100);
        const float4* T4 = (const float4*)(Ts + t * 100);
        float a0 = 0.f, a1 = 0.f, a2 = 0.f, a3 = 0.f, a4 = 0.f,
              a5 = 0.f, a6 = 0.f, a7 = 0.f, a8 = 0.f;
        DOT4(0, a0)
        DOT4(1, a1)
        DOT4(2, a2)  DOT4(3, a2)
        DOT4(4, a3)
        DOT4(5, a4)  DOT4(6, a4)  DOT4(7, a4)
        DOT4(8, a5)  DOT4(9, a5)  DOT4(10, a5) DOT4(11, a5)
        DOT4(12, a6) DOT4(13, a6)
        DOT4(14, a7) DOT4(15, a7) DOT4(16, a7) DOT4(17, a7)
        DOT4(18, a8) DOT4(19, a8) DOT4(20, a8) DOT4(21, a8)
        DOT4(22, a8) DOT4(23, a8) DOT4(24, a8)
        float* zp = Z + row * 300 + t * 12;
        *(float4*)zp       = make_float4(a0, a1, a2, a3);
        *(float4*)(zp + 4) = make_float4(a4, a5, a6, a7);
        zp[8] = a8;
    }
#undef DOT4
    __syncthreads();
    // ---- Ts is DEAD from here; Zout (overlaying it) becomes live ----

    // Stage B: thread = (d = tid&31, g = tid>>5); g<6 -> row g.
    // Writes to Zout (LDS transpose): addr = local_n*2400 + d*75 + v*25 + t
    // -> bank (11d+t)%32, distinct per lane: conflict-free.
    {
        const int d = tid & 31, g = tid >> 5;
        if (g < 6) {
            const int row = g;
            const int zo = (row / 3) * 2400 + d * 75 + (row % 3) * 25;
            const float* zrow = Z + row * 300;
#pragma unroll
            for (int lt = 0; lt < 5; ++lt) {
                const float* vb = Vs + lt * 288 + d;
                const float v0 = vb[0],   v1 = vb[32],  v2 = vb[64],
                            v3 = vb[96],  v4 = vb[128], v5 = vb[160],
                            v6 = vb[192], v7 = vb[224], v8 = vb[256];
                const int t0 = lt * lt, t1 = (lt + 1) * (lt + 1);
#pragma unroll
                for (int t = t0; t < t1; ++t) {
                    const float* zp = zrow + t * 12;
                    float4 za = *(const float4*)zp;
                    float4 zb = *(const float4*)(zp + 4);
                    float acc = zp[8] * v8;
                    acc = fmaf(za.x, v0, acc); acc = fmaf(za.y, v1, acc);
                    acc = fmaf(za.z, v2, acc); acc = fmaf(za.w, v3, acc);
                    acc = fmaf(zb.x, v4, acc); acc = fmaf(zb.y, v5, acc);
                    acc = fmaf(zb.z, v6, acc); acc = fmaf(zb.w, v7, acc);
                    Zout[zo + t] = acc;
                }
            }
        }
    }
    __syncthreads();

    // coalesced copy-out: 4800 floats = 1200 float4, contiguous per block
    float4* og = (float4*)(out + (size_t)n0 * 2400);
    const float4* zo4 = (const float4*)Zout;
    for (int i = tid; i < 1200; i += 256) og[i] = zo4[i];
}

extern "C" void kernel_launch(void* const* d_in, const int* in_sizes, int n_in,
                              void* d_out, int out_size, void* d_ws, size_t ws_size,
                              hipStream_t stream) {
    const float* x    = (const float*)d_in[0];
    const float* y    = (const float*)d_in[1];
    const float* Wx   = (const float*)d_in[2];
    const float* Wy   = (const float*)d_in[3];
    const float* Wz   = (const float*)d_in[4];
    const float* Yin  = (const float*)d_in[5];
    const float* Yout = (const float*)d_in[6];
    const float* wq   = (const float*)d_in[7];
    float* out = (float*)d_out;

    float* Tg = (float*)d_ws;        // 25*100 = 2500 floats
    float* Vg = Tg + 2500;           // 1440 floats (offset 10000B, 16B-aligned)

    precomp<<<631, 256, 0, stream>>>(Wx, Wy, Wz, Yin, Yout, wq, Tg, Vg);
    gaunt_main<<<1024, 256, 0, stream>>>(x, y, Tg, Vg, out);
}